// Round 4
// baseline (2063.259 us; speedup 1.0000x reference)
//
#include <hip/hip_runtime.h>

#define NPT 100
#define KK 10

typedef __attribute__((ext_vector_type(8))) short short8;
typedef __attribute__((ext_vector_type(4))) float float4v;

__device__ __forceinline__ float leaky(float v){ return fmaxf(v, 0.2f*v); }
__device__ __forceinline__ unsigned short bf16r(float x){
  unsigned u = __float_as_uint(x);
  return (unsigned short)((u + 0x7FFFu + ((u>>16)&1u)) >> 16);
}
__device__ __forceinline__ float bf2f(unsigned short h){ return __uint_as_float(((unsigned)h)<<16); }

// d_ws layout. float offsets:
#define WV(w) (1024*(w))        // 9 folded 32x32 fp32 mats: W0f,Wp1,Wq1,W2f,Wp3,Wq3,W4f,Wp5,Wq5
#define W7G_OFF 9216            // W7 g-part folded fp32 [128][512]
// byte offsets:
#define W6B_OFF   299008        // W6 folded bf16 [512][288]  (K-blocks: 0-2 hi,3-5 hi,6-8 lo)
#define W796B_OFF 593920        // W7 96-part folded bf16 [128][288]
#define W8B_OFF   667648        // W8 folded bf16 [32][384]   (0-3 hi,4-7 hi,8-11 lo)

struct PrepP {
  const float* W[9];
  const float* s[9];
  float* ws;
};

__global__ __launch_bounds__(256) void prep_kernel(PrepP p){
  int gid = blockIdx.x*256 + threadIdx.x;
  int gs = gridDim.x*256;
  float* ws = p.ws;
  unsigned short* w6b  = (unsigned short*)((char*)ws + W6B_OFF);
  unsigned short* w796 = (unsigned short*)((char*)ws + W796B_OFF);
  unsigned short* w8b  = (unsigned short*)((char*)ws + W8B_OFF);
  for(int i = gid; i < 9216; i += gs){
    int w = i >> 10, r = i & 1023, o = r >> 5, c = r & 31;
    float v = 0.f;
    switch(w){
      case 0: v = (c < 30) ? p.s[0][o]*p.W[0][o*30 + c] : 0.f; break;
      case 1: v = p.s[1][o]*p.W[1][o*64 + c]; break;
      case 2: v = p.s[1][o]*(p.W[1][o*64 + 32 + c] - p.W[1][o*64 + c]); break;
      case 3: v = p.s[2][o]*p.W[2][o*32 + c]; break;
      case 4: v = p.s[3][o]*p.W[3][o*64 + c]; break;
      case 5: v = p.s[3][o]*(p.W[3][o*64 + 32 + c] - p.W[3][o*64 + c]); break;
      case 6: v = p.s[4][o]*p.W[4][o*32 + c]; break;
      case 7: v = p.s[5][o]*p.W[5][o*64 + c]; break;
      case 8: v = p.s[5][o]*(p.W[5][o*64 + 32 + c] - p.W[5][o*64 + c]); break;
    }
    ws[i] = v;
  }
  for(int i = gid; i < 65536; i += gs){
    int o = i >> 9, c = i & 511;
    ws[W7G_OFF + i] = p.s[7][o]*p.W[7][o*608 + c];
  }
  for(int i = gid; i < 147456; i += gs){
    int o = i/288, cc = i - o*288, kb = cc >> 5, k = cc & 31;
    int sc = (kb % 3)*32 + k;
    float w = p.s[6][o]*p.W[6][o*96 + sc];
    unsigned short h = bf16r(w);
    w6b[i] = (kb < 6) ? h : bf16r(w - bf2f(h));
  }
  for(int i = gid; i < 36864; i += gs){
    int o = i/288, cc = i - o*288, kb = cc >> 5, k = cc & 31;
    int sc = 512 + (kb % 3)*32 + k;
    float w = p.s[7][o]*p.W[7][o*608 + sc];
    unsigned short h = bf16r(w);
    w796[i] = (kb < 6) ? h : bf16r(w - bf2f(h));
  }
  for(int i = gid; i < 12288; i += gs){
    int o = i/384, cc = i - o*384, kb = cc >> 5, k = cc & 31;
    int sc = (kb & 3)*32 + k;
    float w = p.s[8][o]*p.W[8][o*128 + sc];
    unsigned short h = bf16r(w);
    w8b[i] = (kb < 8) ? h : bf16r(w - bf2f(h));
  }
}

// XBIG: [100][96] as 24 quads/row, XOR-swizzled within 8-quad groups
__device__ __forceinline__ int xcq(int n, int q){ return n*24 + (q ^ (n & 7)); }
// PREG P: [100][32] as 8 quads/row, swizzled
__device__ __forceinline__ int pq(int j, int q){ return j*8 + (q ^ (j & 7)); }

__device__ __forceinline__ void loadxg(const float* XB, int row, int gq, float* xr){
  #pragma unroll
  for(int q = 0; q < 8; ++q){
    float4v v = *(const float4v*)&XB[xcq(row, gq + q) << 2];
    xr[q*4+0] = v.x; xr[q*4+1] = v.y; xr[q*4+2] = v.z; xr[q*4+3] = v.w;
  }
}
__device__ __forceinline__ float dot32(const float* wrow, const float* xr){
  float a0 = 0.f, a1 = 0.f, a2 = 0.f, a3 = 0.f;
  #pragma unroll
  for(int q = 0; q < 8; ++q){
    float4v w = *(const float4v*)&wrow[q*4];
    a0 = fmaf(w.x, xr[q*4+0], a0);
    a1 = fmaf(w.y, xr[q*4+1], a1);
    a2 = fmaf(w.z, xr[q*4+2], a2);
    a3 = fmaf(w.w, xr[q*4+3], a3);
  }
  return (a0+a1)+(a2+a3);
}
// bf16 hi/lo fragments from swizzled XBIG group g (8 elems starting at quad*8)
__device__ __forceinline__ void buildB2(const float* XB, int row, int g, int quad,
                                        short8* bh, short8* bl){
  float4v v0 = *(const float4v*)&XB[xcq(row, g*8 + quad*2)     << 2];
  float4v v1 = *(const float4v*)&XB[xcq(row, g*8 + quad*2 + 1) << 2];
  float xv[8] = {v0.x, v0.y, v0.z, v0.w, v1.x, v1.y, v1.z, v1.w};
  short8 h, l;
  #pragma unroll
  for(int j = 0; j < 8; ++j){
    unsigned short hh = bf16r(xv[j]);
    h[j] = (short)hh;
    l[j] = (short)bf16r(xv[j] - bf2f(hh));
  }
  *bh = h; *bl = l;
}
// contiguous variant (H2)
__device__ __forceinline__ void buildB(const float* src, short8* bh, short8* bl){
  float4v v0 = *(const float4v*)&src[0];
  float4v v1 = *(const float4v*)&src[4];
  float xv[8] = {v0.x, v0.y, v0.z, v0.w, v1.x, v1.y, v1.z, v1.w};
  short8 h, l;
  #pragma unroll
  for(int j = 0; j < 8; ++j){
    unsigned short hh = bf16r(xv[j]);
    h[j] = (short)hh;
    l[j] = (short)bf16r(xv[j] - bf2f(hh));
  }
  *bh = h; *bl = l;
}

struct MainP {
  const float* obs;
  const float* W9;
  const float* t[9];
  const float* ws;
  float* out;
};

__global__ __launch_bounds__(512, 4) void dgcnn(MainP p){
  const int b = blockIdx.x;
  const int tid = threadIdx.x;
  const int lane = tid & 63, wv = tid >> 6;
  const int quad = lane >> 4, l15 = lane & 15;

  // LDS: 38400 + 12800 + 12288 + 400 + 128 + 1000 = 65016 B
  __shared__ __align__(16) float XBIG[9600];   // 3 col-groups of 32 (swizzled quads)
  __shared__ __align__(16) float PREG[3200];   // P[100][32] swizzled -> H2[16][132]
  __shared__ __align__(16) float WST[3072];    // [0:1024) Wp / g, [1024:2048) Wq / Rg, [2048:3072) conv-w
  __shared__ __align__(16) float XX[100];
  __shared__ __align__(16) float TMP[32];
  __shared__ unsigned char IDXB[1000];

  const float* ws = p.ws;
  const unsigned short* w6b  = (const unsigned short*)((const char*)ws + W6B_OFF);
  const unsigned short* w796 = (const unsigned short*)((const char*)ws + W796B_OFF);
  const unsigned short* w8b  = (const unsigned short*)((const char*)ws + W8B_OFF);

  // ---- stage obs -> XBIG group 0 (zero-padded [100][32], swizzled) + W0f ----
  for(int i = tid; i < 3200; i += 512){
    int n = i >> 5, c = i & 31;
    float v = (c < 30) ? p.obs[(size_t)b*3000 + n*30 + c] : 0.f;
    XBIG[(xcq(n, c >> 2) << 2) | (c & 3)] = v;
  }
  for(int i = tid; i < 1024; i += 512) WST[i] = ws[WV(0) + i];
  __syncthreads();

  // ---- conv0: group0(obs) -> group2(x0); 4x128 threads, 8 outs each ----
  {
    int oh = tid >> 7, n = tid & 127;
    if(n < NPT){
      float xr[32]; loadxg(XBIG, n, 0, xr);
      float o8[8];
      #pragma unroll
      for(int oi = 0; oi < 8; ++oi){
        int o = oh*8 + oi;
        o8[oi] = leaky(dot32(&WST[o*32], xr) + p.t[0][o]);
      }
      *(float4v*)&XBIG[xcq(n, 16 + oh*2)     << 2] = *(float4v*)&o8[0];
      *(float4v*)&XBIG[xcq(n, 16 + oh*2 + 1) << 2] = *(float4v*)&o8[4];
    }
  }
  __syncthreads();

  // ---- 3 edge layers ----
  // groups: L0: in g2(x0), Q g1, out g0(x1), scratch raw cols [0,32)
  //         L1: in g0(x1), Q g2, out g1(x2), scratch raw cols [32,64)
  //         L2: in g1(x2), Q in-reg, out g2(x3), scratch raw cols [64,96)
  const int XINq[3] = {16, 0, 8};
  const int QOFq[3] = {8, 16, 0};
  const int OUTq[3] = {0, 8, 16};
  const int OUTc[3] = {0, 32, 64};
  const int WPI[3]  = {1, 4, 7};

  for(int L = 0; L < 3; ++L){
    // S1: stage Wp,Wq; xx
    for(int i = tid; i < 2048; i += 512) WST[i] = ws[WV(WPI[L]) + i];
    __syncthreads();   // (Wq load indexes WV(WPI)+i spanning both mats)
    if(tid < NPT){
      float xr[32]; loadxg(XBIG, tid, XINq[L], xr);
      float a = 0.f;
      #pragma unroll
      for(int c = 0; c < 32; ++c) a = fmaf(xr[c], xr[c], a);
      XX[tid] = a;
    }
    __syncthreads();

    // S2: kNN halves (0-255) | P (256-355) | stage conv-w + Q' (384-511)
    if(tid < 256){
      int n = tid & 127, h = tid >> 7;
      if(n < NPT){
        float xr[32]; loadxg(XBIG, n, XINq[L], xr);
        const float xxn = XX[n];
        float bv[KK]; int bj[KK];
        #pragma unroll
        for(int k = 0; k < KK; ++k){ bv[k] = -3.4e38f; bj[k] = 0; }
        const int m0 = h*50;
        #pragma unroll 1
        for(int m = m0; m < m0 + 50; ++m){
          float a0 = 0.f, a1 = 0.f, a2 = 0.f, a3 = 0.f;
          #pragma unroll
          for(int q = 0; q < 8; ++q){
            float4v v = *(const float4v*)&XBIG[xcq(m, XINq[L] + q) << 2]; // broadcast
            a0 = fmaf(xr[q*4+0], v.x, a0);
            a1 = fmaf(xr[q*4+1], v.y, a1);
            a2 = fmaf(xr[q*4+2], v.z, a2);
            a3 = fmaf(xr[q*4+3], v.w, a3);
          }
          float d = 2.0f*((a0+a1)+(a2+a3)) - xxn - XX[m];
          if(d > bv[KK-1]){   // strict >: earlier m wins ties
            float cv = d; int ci = m;
            #pragma unroll
            for(int jj = 0; jj < KK; ++jj){
              bool sw = cv > bv[jj];
              float tv = bv[jj]; int ti = bj[jj];
              bv[jj] = sw ? cv : tv; bj[jj] = sw ? ci : ti;
              cv = sw ? tv : cv;    ci = sw ? ti : ci;
            }
          }
        }
        // write half list to raw scratch (rotated cols break same-bank rows)
        float* rowraw = &XBIG[n*96 + OUTc[L]];
        unsigned char* rowb = (unsigned char*)rowraw;
        #pragma unroll
        for(int k = 0; k < KK; ++k){
          int slot = (h*10 + k + n) % 20;
          rowraw[slot] = bv[k];
          rowb[80 + slot] = (unsigned char)bj[k];
        }
      }
    } else if(tid < 384){
      int j = tid - 256;
      if(j < NPT){
        float xr[32]; loadxg(XBIG, j, XINq[L], xr);
        #pragma unroll 1
        for(int og = 0; og < 4; ++og){
          float t[8];
          #pragma unroll
          for(int oi = 0; oi < 8; ++oi) t[oi] = dot32(&WST[(og*8 + oi)*32], xr);
          *(float4v*)&PREG[pq(j, og*2)     << 2] = *(float4v*)&t[0];
          *(float4v*)&PREG[pq(j, og*2 + 1) << 2] = *(float4v*)&t[4];
        }
      }
    } else {
      if(L < 2){
        int wci = (L == 0) ? 3 : 6;
        for(int i = tid - 384; i < 1024; i += 128) WST[2048 + i] = ws[WV(wci) + i];
        int n = tid - 384;
        if(n < NPT){
          const float* ta = p.t[1 + 2*L];
          float xr[32]; loadxg(XBIG, n, XINq[L], xr);
          #pragma unroll 1
          for(int og = 0; og < 4; ++og){
            float t[8];
            #pragma unroll
            for(int oi = 0; oi < 8; ++oi)
              t[oi] = dot32(&WST[1024 + (og*8 + oi)*32], xr) + ta[og*8 + oi];  // Q' = Q + t_a
            *(float4v*)&XBIG[xcq(n, QOFq[L] + og*2)     << 2] = *(float4v*)&t[0];
            *(float4v*)&XBIG[xcq(n, QOFq[L] + og*2 + 1) << 2] = *(float4v*)&t[4];
          }
        }
      }
    }
    __syncthreads();

    // S3: merge the two sorted half-lists (stable, half0 wins ties)
    if(tid < NPT){
      const int n = tid;
      const float* rowraw = &XBIG[n*96 + OUTc[L]];
      const unsigned char* rowb = (const unsigned char*)rowraw;
      int ia = 0, ib = 0;
      #pragma unroll
      for(int k = 0; k < KK; ++k){
        bool canA = ia < 10, canB = ib < 10;
        float va = canA ? rowraw[(ia + n) % 20]      : -3.4e38f;
        float vb = canB ? rowraw[(10 + ib + n) % 20] : -3.4e38f;
        bool takeb = canB && (!canA || (vb > va));
        int slot = takeb ? ((10 + ib + n) % 20) : ((ia + n) % 20);
        IDXB[n*KK + k] = rowb[80 + slot];
        ia += takeb ? 0 : 1;
        ib += takeb ? 1 : 0;
      }
    }
    __syncthreads();

    // S4
    if(L < 2){
      // conv2: thread=(n, o-octet); oct wave-pair-uniform -> broadcast weight reads
      int n = tid & 127, oct = tid >> 7, ob = oct*8;
      if(n < NPT){
        const float* tb = p.t[2 + 2*L];
        float qp[32]; loadxg(XBIG, n, QOFq[L], qp);   // Q' (incl t_a)
        float acc[8];
        #pragma unroll
        for(int o = 0; o < 8; ++o) acc[o] = -3.4e38f;
        #pragma unroll 1
        for(int k = 0; k < KK; ++k){
          int j = (int)IDXB[n*KK + k];
          float e[32];
          #pragma unroll
          for(int q = 0; q < 8; ++q){
            float4v pv = *(const float4v*)&PREG[pq(j, q) << 2];
            e[q*4+0] = leaky(pv.x + qp[q*4+0]);
            e[q*4+1] = leaky(pv.y + qp[q*4+1]);
            e[q*4+2] = leaky(pv.z + qp[q*4+2]);
            e[q*4+3] = leaky(pv.w + qp[q*4+3]);
          }
          #pragma unroll
          for(int oi = 0; oi < 8; ++oi){
            float d0 = 0.f, d1 = 0.f;
            #pragma unroll
            for(int q = 0; q < 8; ++q){
              float4v w = *(const float4v*)&WST[2048 + (ob + oi)*32 + q*4];
              d0 = fmaf(w.x, e[q*4+0], d0); d1 = fmaf(w.y, e[q*4+1], d1);
              d0 = fmaf(w.z, e[q*4+2], d0); d1 = fmaf(w.w, e[q*4+3], d1);
            }
            acc[oi] = fmaxf(acc[oi], d0 + d1);
          }
        }
        float y[8];
        #pragma unroll
        for(int oi = 0; oi < 8; ++oi) y[oi] = leaky(acc[oi] + tb[ob + oi]);
        *(float4v*)&XBIG[xcq(n, OUTq[L] + oct*2)     << 2] = *(float4v*)&y[0];
        *(float4v*)&XBIG[xcq(n, OUTq[L] + oct*2 + 1) << 2] = *(float4v*)&y[4];
      }
    } else {
      // layer 3 final: x3 = leaky(max_k P[j] + Q + t5); pm first, then fold Q per octet
      if(tid < NPT){
        const int n = tid;
        float pm[32];
        #pragma unroll
        for(int o = 0; o < 32; ++o) pm[o] = -3.4e38f;
        #pragma unroll 1
        for(int k = 0; k < KK; ++k){
          int j = (int)IDXB[n*KK + k];
          #pragma unroll
          for(int q = 0; q < 8; ++q){
            float4v pv = *(const float4v*)&PREG[pq(j, q) << 2];
            pm[q*4+0] = fmaxf(pm[q*4+0], pv.x);
            pm[q*4+1] = fmaxf(pm[q*4+1], pv.y);
            pm[q*4+2] = fmaxf(pm[q*4+2], pv.z);
            pm[q*4+3] = fmaxf(pm[q*4+3], pv.w);
          }
        }
        float xr[32]; loadxg(XBIG, n, XINq[L], xr);
        const float* t5 = p.t[5];
        #pragma unroll 1
        for(int og = 0; og < 4; ++og){
          float y[8];
          #pragma unroll
          for(int oi = 0; oi < 8; ++oi){
            int o = og*8 + oi;
            float qv = dot32(&WST[1024 + o*32], xr);
            y[oi] = leaky(pm[o] + qv + t5[o]);
          }
          *(float4v*)&XBIG[xcq(n, OUTq[L] + og*2)     << 2] = *(float4v*)&y[0];
          *(float4v*)&XBIG[xcq(n, OUTq[L] + og*2 + 1) << 2] = *(float4v*)&y[4];
        }
      }
    }
    __syncthreads();
  }

  // ---- W6 (512x96) MFMA bf16x3, in-register max over n -> g in WST[0:512) ----
  {
    float4v gmax[4];
    #pragma unroll
    for(int i = 0; i < 4; ++i){ gmax[i][0]=-3.4e38f; gmax[i][1]=-3.4e38f; gmax[i][2]=-3.4e38f; gmax[i][3]=-3.4e38f; }
    #pragma unroll 1
    for(int nt = 0; nt < 7; ++nt){
      int row = nt*16 + l15; if(row > 99) row = 99;   // dup row ok under max
      short8 Bh[3], Bl[3];
      #pragma unroll
      for(int g = 0; g < 3; ++g) buildB2(XBIG, row, g, quad, &Bh[g], &Bl[g]);
      #pragma unroll 1
      for(int mtl = 0; mtl < 4; ++mtl){
        int T = wv*4 + mtl;
        const unsigned short* ar = w6b + (T*16 + l15)*288 + quad*8;
        float4v d = {0.f, 0.f, 0.f, 0.f};
        #pragma unroll
        for(int kb = 0; kb < 9; ++kb){
          short8 a = *(const short8*)(ar + kb*32);
          short8 bb = (kb < 3) ? Bh[kb] : ((kb < 6) ? Bl[kb-3] : Bh[kb-6]);
          d = __builtin_amdgcn_mfma_f32_16x16x32_bf16(a, bb, d, 0, 0, 0);
        }
        #pragma unroll
        for(int r = 0; r < 4; ++r) gmax[mtl][r] = fmaxf(gmax[mtl][r], d[r]);
      }
    }
    #pragma unroll 1
    for(int mtl = 0; mtl < 4; ++mtl){
      float4v m = gmax[mtl];
      #pragma unroll
      for(int bit = 1; bit < 16; bit <<= 1){
        m[0] = fmaxf(m[0], __shfl_xor(m[0], bit, 64));
        m[1] = fmaxf(m[1], __shfl_xor(m[1], bit, 64));
        m[2] = fmaxf(m[2], __shfl_xor(m[2], bit, 64));
        m[3] = fmaxf(m[3], __shfl_xor(m[3], bit, 64));
      }
      if(l15 == 0){
        int T = wv*4 + mtl;
        #pragma unroll
        for(int r = 0; r < 4; ++r){
          int o = T*16 + quad*4 + r;
          WST[o] = leaky(m[r] + p.t[6][o]);
        }
      }
    }
  }
  __syncthreads();

  // ---- Rg[o] = W7g . g  (4 threads per o) -> WST[512:640) ----
  {
    int o = tid >> 2, qtr = tid & 3;
    const float* wr = &ws[W7G_OFF + o*512 + qtr*128];
    const float* gr = &WST[qtr*128];
    float a0 = 0.f, a1 = 0.f, a2 = 0.f, a3 = 0.f;
    #pragma unroll 4
    for(int c4 = 0; c4 < 32; ++c4){
      float4v w = *(const float4v*)&wr[c4*4];
      float4v g = *(const float4v*)&gr[c4*4];
      a0 = fmaf(w.x, g.x, a0); a1 = fmaf(w.y, g.y, a1);
      a2 = fmaf(w.z, g.z, a2); a3 = fmaf(w.w, g.w, a3);
    }
    float a = (a0+a1)+(a2+a3);
    a += __shfl_xor(a, 1, 64);
    a += __shfl_xor(a, 2, 64);
    if(qtr == 0) WST[512 + o] = a;
  }
  __syncthreads();

  // ---- tail: per 16-point chunk: W7(96-part) MFMA (1 tile/wave) -> h2; W8; W9 ----
  float* H2 = PREG;   // [16][132]
  #pragma unroll 1
  for(int nc = 0; nc < 7; ++nc){
    int n0 = nc*16;
    int row = n0 + l15; if(row > 99) row = 99;
    {
      short8 Bh[3], Bl[3];
      #pragma unroll
      for(int g = 0; g < 3; ++g) buildB2(XBIG, row, g, quad, &Bh[g], &Bl[g]);
      const int Mt = wv;
      const unsigned short* ar = w796 + (Mt*16 + l15)*288 + quad*8;
      float4v d = {0.f, 0.f, 0.f, 0.f};
      #pragma unroll
      for(int kb = 0; kb < 9; ++kb){
        short8 a = *(const short8*)(ar + kb*32);
        short8 bb = (kb < 3) ? Bh[kb] : ((kb < 6) ? Bl[kb-3] : Bh[kb-6]);
        d = __builtin_amdgcn_mfma_f32_16x16x32_bf16(a, bb, d, 0, 0, 0);
      }
      float y[4];
      #pragma unroll
      for(int r = 0; r < 4; ++r){
        int ch = Mt*16 + quad*4 + r;
        y[r] = leaky(d[r] + WST[512 + ch] + p.t[7][ch]);
      }
      *(float4v*)&H2[l15*132 + Mt*16 + quad*4] = *(float4v*)&y[0];
    }
    __syncthreads();
    if(wv < 2){
      short8 Ch[4], Cl[4];
      #pragma unroll
      for(int g = 0; g < 4; ++g) buildB(&H2[l15*132 + g*32 + quad*8], &Ch[g], &Cl[g]);
      const unsigned short* ar = w8b + (wv*16 + l15)*384 + quad*8;
      float4v d = {0.f, 0.f, 0.f, 0.f};
      #pragma unroll
      for(int kb = 0; kb < 12; ++kb){
        short8 a = *(const short8*)(ar + kb*32);
        short8 bb = (kb < 4) ? Ch[kb] : ((kb < 8) ? Cl[kb-4] : Ch[kb-8]);
        d = __builtin_amdgcn_mfma_f32_16x16x32_bf16(a, bb, d, 0, 0, 0);
      }
      float partial = 0.f;
      #pragma unroll
      for(int r = 0; r < 4; ++r){
        int o = wv*16 + quad*4 + r;
        float h3 = leaky(d[r] + p.t[8][o]);
        partial = fmaf(p.W9[o], h3, partial);
      }
      partial += __shfl_xor(partial, 16, 64);
      partial += __shfl_xor(partial, 32, 64);
      if(lane < 16) TMP[wv*16 + lane] = partial;
    }
    __syncthreads();
    if(tid < 16 && (n0 + tid) < NPT)
      p.out[(size_t)b*NPT + n0 + tid] = TMP[tid] + TMP[16 + tid];
    __syncthreads();
  }
}

extern "C" void kernel_launch(void* const* d_in, const int* in_sizes, int n_in,
                              void* d_out, int out_size, void* d_ws, size_t ws_size,
                              hipStream_t stream) {
  (void)n_in; (void)out_size; (void)ws_size;
  PrepP pp;
  for(int i = 0; i < 9; ++i) pp.W[i] = (const float*)d_in[1 + i];
  for(int i = 0; i < 9; ++i) pp.s[i] = (const float*)d_in[11 + 2*i];
  pp.ws = (float*)d_ws;
  prep_kernel<<<256, 256, 0, stream>>>(pp);

  MainP mp;
  mp.obs = (const float*)d_in[0];
  mp.W9  = (const float*)d_in[10];
  for(int i = 0; i < 9; ++i) mp.t[i] = (const float*)d_in[12 + 2*i];
  mp.ws  = (const float*)d_ws;
  mp.out = (float*)d_out;
  const int B = in_sizes[0] / 3000;
  dgcnn<<<B, 512, 0, stream>>>(mp);
}

// Round 5
// 1147.741 us; speedup vs baseline: 1.7977x; 1.7977x over previous
//
#include <hip/hip_runtime.h>

#define NPT 100
#define KK 10

typedef __attribute__((ext_vector_type(8))) short short8;
typedef __attribute__((ext_vector_type(4))) float float4v;

__device__ __forceinline__ float leaky(float v){ return fmaxf(v, 0.2f*v); }
__device__ __forceinline__ unsigned short bf16r(float x){
  unsigned u = __float_as_uint(x);
  return (unsigned short)((u + 0x7FFFu + ((u>>16)&1u)) >> 16);
}
__device__ __forceinline__ float bf2f(unsigned short h){ return __uint_as_float(((unsigned)h)<<16); }

// d_ws layout. float offsets:
#define WV(w) (1024*(w))        // 9 folded 32x32 fp32 mats: W0f,Wp1,Wq1,W2f,Wp3,Wq3,W4f,Wp5,Wq5
#define W7G_OFF 9216            // W7 g-part folded fp32 [128][512]
// byte offsets:
#define W6B_OFF   299008        // W6 folded bf16 [512][288]  (K-blocks: 0-2 hi,3-5 hi,6-8 lo)
#define W796B_OFF 593920        // W7 96-part folded bf16 [128][288]
#define W8B_OFF   667648        // W8 folded bf16 [32][384]   (0-3 hi,4-7 hi,8-11 lo)

struct PrepP {
  const float* W[9];
  const float* s[9];
  float* ws;
};

__global__ __launch_bounds__(256) void prep_kernel(PrepP p){
  int gid = blockIdx.x*256 + threadIdx.x;
  int gs = gridDim.x*256;
  float* ws = p.ws;
  unsigned short* w6b  = (unsigned short*)((char*)ws + W6B_OFF);
  unsigned short* w796 = (unsigned short*)((char*)ws + W796B_OFF);
  unsigned short* w8b  = (unsigned short*)((char*)ws + W8B_OFF);
  for(int i = gid; i < 9216; i += gs){
    int w = i >> 10, r = i & 1023, o = r >> 5, c = r & 31;
    float v = 0.f;
    switch(w){
      case 0: v = (c < 30) ? p.s[0][o]*p.W[0][o*30 + c] : 0.f; break;
      case 1: v = p.s[1][o]*p.W[1][o*64 + c]; break;
      case 2: v = p.s[1][o]*(p.W[1][o*64 + 32 + c] - p.W[1][o*64 + c]); break;
      case 3: v = p.s[2][o]*p.W[2][o*32 + c]; break;
      case 4: v = p.s[3][o]*p.W[3][o*64 + c]; break;
      case 5: v = p.s[3][o]*(p.W[3][o*64 + 32 + c] - p.W[3][o*64 + c]); break;
      case 6: v = p.s[4][o]*p.W[4][o*32 + c]; break;
      case 7: v = p.s[5][o]*p.W[5][o*64 + c]; break;
      case 8: v = p.s[5][o]*(p.W[5][o*64 + 32 + c] - p.W[5][o*64 + c]); break;
    }
    ws[i] = v;
  }
  for(int i = gid; i < 65536; i += gs){
    int o = i >> 9, c = i & 511;
    ws[W7G_OFF + i] = p.s[7][o]*p.W[7][o*608 + c];
  }
  for(int i = gid; i < 147456; i += gs){
    int o = i/288, cc = i - o*288, kb = cc >> 5, k = cc & 31;
    int sc = (kb % 3)*32 + k;
    float w = p.s[6][o]*p.W[6][o*96 + sc];
    unsigned short h = bf16r(w);
    w6b[i] = (kb < 6) ? h : bf16r(w - bf2f(h));
  }
  for(int i = gid; i < 36864; i += gs){
    int o = i/288, cc = i - o*288, kb = cc >> 5, k = cc & 31;
    int sc = 512 + (kb % 3)*32 + k;
    float w = p.s[7][o]*p.W[7][o*608 + sc];
    unsigned short h = bf16r(w);
    w796[i] = (kb < 6) ? h : bf16r(w - bf2f(h));
  }
  for(int i = gid; i < 12288; i += gs){
    int o = i/384, cc = i - o*384, kb = cc >> 5, k = cc & 31;
    int sc = (kb & 3)*32 + k;
    float w = p.s[8][o]*p.W[8][o*128 + sc];
    unsigned short h = bf16r(w);
    w8b[i] = (kb < 8) ? h : bf16r(w - bf2f(h));
  }
}

// XBIG: [100][96] as 24 quads/row, XOR-swizzled within 8-quad groups
__device__ __forceinline__ int xcq(int n, int q){ return n*24 + (q ^ (n & 7)); }
// PREG P: [100][32] as 8 quads/row, swizzled
__device__ __forceinline__ int pq(int j, int q){ return j*8 + (q ^ (j & 7)); }

__device__ __forceinline__ void loadxg(const float* XB, int row, int gq, float* xr){
  #pragma unroll
  for(int q = 0; q < 8; ++q){
    float4v v = *(const float4v*)&XB[xcq(row, gq + q) << 2];
    xr[q*4+0] = v.x; xr[q*4+1] = v.y; xr[q*4+2] = v.z; xr[q*4+3] = v.w;
  }
}
__device__ __forceinline__ float dot32(const float* wrow, const float* xr){
  float a0 = 0.f, a1 = 0.f, a2 = 0.f, a3 = 0.f;
  #pragma unroll
  for(int q = 0; q < 8; ++q){
    float4v w = *(const float4v*)&wrow[q*4];
    a0 = fmaf(w.x, xr[q*4+0], a0);
    a1 = fmaf(w.y, xr[q*4+1], a1);
    a2 = fmaf(w.z, xr[q*4+2], a2);
    a3 = fmaf(w.w, xr[q*4+3], a3);
  }
  return (a0+a1)+(a2+a3);
}
// bf16 hi/lo fragments from swizzled XBIG group g (8 elems at quad*8)
__device__ __forceinline__ void buildB2(const float* XB, int row, int g, int quad,
                                        short8* bh, short8* bl){
  float4v v0 = *(const float4v*)&XB[xcq(row, g*8 + quad*2)     << 2];
  float4v v1 = *(const float4v*)&XB[xcq(row, g*8 + quad*2 + 1) << 2];
  float xv[8] = {v0.x, v0.y, v0.z, v0.w, v1.x, v1.y, v1.z, v1.w};
  short8 h, l;
  #pragma unroll
  for(int j = 0; j < 8; ++j){
    unsigned short hh = bf16r(xv[j]);
    h[j] = (short)hh;
    l[j] = (short)bf16r(xv[j] - bf2f(hh));
  }
  *bh = h; *bl = l;
}
// contiguous variant (H2)
__device__ __forceinline__ void buildB(const float* src, short8* bh, short8* bl){
  float4v v0 = *(const float4v*)&src[0];
  float4v v1 = *(const float4v*)&src[4];
  float xv[8] = {v0.x, v0.y, v0.z, v0.w, v1.x, v1.y, v1.z, v1.w};
  short8 h, l;
  #pragma unroll
  for(int j = 0; j < 8; ++j){
    unsigned short hh = bf16r(xv[j]);
    h[j] = (short)hh;
    l[j] = (short)bf16r(xv[j] - bf2f(hh));
  }
  *bh = h; *bl = l;
}

struct MainP {
  const float* obs;
  const float* W9;
  const float* t[9];
  const float* ws;
  float* out;
};

__global__ __launch_bounds__(256, 2) void dgcnn(MainP p){
  const int b = blockIdx.x;
  const int tid = threadIdx.x;
  const int lane = tid & 63, wv = tid >> 6;
  const int quad = lane >> 4, l15 = lane & 15;

  // LDS: 38400 + 12800 + 12288 + 400 + 128 + 1000 = 65016 B -> 2 blocks/CU
  __shared__ __align__(16) float XBIG[9600];   // 3 col-groups of 32 (swizzled quads)
  __shared__ __align__(16) float PREG[3200];   // P[100][32] swizzled -> H2[16][132]
  __shared__ __align__(16) float WST[3072];    // [0:1024) Wp/g, [1024:2048) Wq/Rg, [2048:3072) conv-w
  __shared__ __align__(16) float XX[100];
  __shared__ __align__(16) float TMP[32];
  __shared__ unsigned char IDXB[1000];

  const float* ws = p.ws;
  const unsigned short* w6b  = (const unsigned short*)((const char*)ws + W6B_OFF);
  const unsigned short* w796 = (const unsigned short*)((const char*)ws + W796B_OFF);
  const unsigned short* w8b  = (const unsigned short*)((const char*)ws + W8B_OFF);

  // ---- stage obs -> XBIG group 0 (zero-padded [100][32], swizzled) + W0f ----
  for(int i = tid; i < 3200; i += 256){
    int n = i >> 5, c = i & 31;
    float v = (c < 30) ? p.obs[(size_t)b*3000 + n*30 + c] : 0.f;
    XBIG[(xcq(n, c >> 2) << 2) | (c & 3)] = v;
  }
  for(int i = tid; i < 1024; i += 256) WST[i] = ws[WV(0) + i];
  __syncthreads();

  // ---- conv0: group0(obs) -> group2(x0); 2x128 threads, 16 outs each ----
  {
    int oh = tid >> 7, n = tid & 127;
    if(n < NPT){
      float xr[32]; loadxg(XBIG, n, 0, xr);
      float o16[16];
      #pragma unroll
      for(int oi = 0; oi < 16; ++oi){
        int o = oh*16 + oi;
        o16[oi] = leaky(dot32(&WST[o*32], xr) + p.t[0][o]);
      }
      #pragma unroll
      for(int q = 0; q < 4; ++q)
        *(float4v*)&XBIG[xcq(n, 16 + oh*4 + q) << 2] = *(float4v*)&o16[q*4];
    }
  }
  __syncthreads();

  // ---- 3 edge layers ----
  // L0: in g2(x0), Q' g1, out g0(x1);  L1: in g0, Q' g2, out g1;  L2: in g1, out g2
  const int XINq[3] = {16, 0, 8};
  const int QOFq[3] = {8, 16, 0};
  const int OUTq[3] = {0, 8, 16};
  const int WPI[3]  = {1, 4, 7};

  for(int L = 0; L < 3; ++L){
    // S1: stage Wp+Wq; xx (single barrier)
    for(int i = tid; i < 2048; i += 256) WST[i] = ws[WV(WPI[L]) + i];
    if(tid < NPT){
      float xr[32]; loadxg(XBIG, tid, XINq[L], xr);
      float a = 0.f;
      #pragma unroll
      for(int c = 0; c < 32; ++c) a = fmaf(xr[c], xr[c], a);
      XX[tid] = a;
    }
    __syncthreads();

    // S2: kNN (0-99) | P + Q' (128-227) | conv-w stage (228-255)
    if(tid < 128){
      if(tid < NPT){
        const int n = tid;
        float xr[32]; loadxg(XBIG, n, XINq[L], xr);
        const float xxn = XX[n];
        float bv[KK]; int bj[KK];
        #pragma unroll
        for(int k = 0; k < KK; ++k){ bv[k] = -3.4e38f; bj[k] = 0; }
        #pragma unroll 1
        for(int m = 0; m < NPT; ++m){
          float a0 = 0.f, a1 = 0.f, a2 = 0.f, a3 = 0.f;
          #pragma unroll
          for(int q = 0; q < 8; ++q){
            float4v v = *(const float4v*)&XBIG[xcq(m, XINq[L] + q) << 2]; // broadcast
            a0 = fmaf(xr[q*4+0], v.x, a0);
            a1 = fmaf(xr[q*4+1], v.y, a1);
            a2 = fmaf(xr[q*4+2], v.z, a2);
            a3 = fmaf(xr[q*4+3], v.w, a3);
          }
          float d = 2.0f*((a0+a1)+(a2+a3)) - xxn - XX[m];
          if(d > bv[KK-1]){   // strict >: earlier m wins ties (matches lax.top_k)
            float cv = d; int ci = m;
            #pragma unroll
            for(int jj = 0; jj < KK; ++jj){
              bool sw = cv > bv[jj];
              float tv = bv[jj]; int ti = bj[jj];
              bv[jj] = sw ? cv : tv; bj[jj] = sw ? ci : ti;
              cv = sw ? tv : cv;    ci = sw ? ti : ci;
            }
          }
        }
        #pragma unroll
        for(int k = 0; k < KK; ++k) IDXB[n*KK + k] = (unsigned char)bj[k];
      }
    } else if(tid < 228){
      int j = tid - 128;
      if(j < NPT){
        float xr[32]; loadxg(XBIG, j, XINq[L], xr);
        #pragma unroll 1
        for(int og = 0; og < 4; ++og){
          float t[8];
          #pragma unroll
          for(int oi = 0; oi < 8; ++oi) t[oi] = dot32(&WST[(og*8 + oi)*32], xr);
          *(float4v*)&PREG[pq(j, og*2)     << 2] = *(float4v*)&t[0];
          *(float4v*)&PREG[pq(j, og*2 + 1) << 2] = *(float4v*)&t[4];
        }
        if(L < 2){
          const float* ta = p.t[1 + 2*L];
          #pragma unroll 1
          for(int og = 0; og < 4; ++og){
            float t[8];
            #pragma unroll
            for(int oi = 0; oi < 8; ++oi)
              t[oi] = dot32(&WST[1024 + (og*8 + oi)*32], xr) + ta[og*8 + oi]; // Q' = Q + t_a
            *(float4v*)&XBIG[xcq(j, QOFq[L] + og*2)     << 2] = *(float4v*)&t[0];
            *(float4v*)&XBIG[xcq(j, QOFq[L] + og*2 + 1) << 2] = *(float4v*)&t[4];
          }
        }
      }
    } else {
      if(L < 2){
        int wci = (L == 0) ? 3 : 6;
        for(int i = tid - 228; i < 1024; i += 28) WST[2048 + i] = ws[WV(wci) + i];
      }
    }
    __syncthreads();

    // S4
    if(L < 2){
      // conv2: item=(n, o-octet); one k-edge at a time (low reg pressure)
      const float* tb = p.t[2 + 2*L];
      for(int it = tid; it < 400; it += 256){
        int n = it % 100, oct = it / 100, ob = oct*8;
        float qp[32]; loadxg(XBIG, n, QOFq[L], qp);   // Q' (incl t_a)
        float acc[8];
        #pragma unroll
        for(int o = 0; o < 8; ++o) acc[o] = -3.4e38f;
        #pragma unroll 1
        for(int k = 0; k < KK; ++k){
          int j = (int)IDXB[n*KK + k];
          float e[32];
          #pragma unroll
          for(int q = 0; q < 8; ++q){
            float4v pv = *(const float4v*)&PREG[pq(j, q) << 2];
            e[q*4+0] = leaky(pv.x + qp[q*4+0]);
            e[q*4+1] = leaky(pv.y + qp[q*4+1]);
            e[q*4+2] = leaky(pv.z + qp[q*4+2]);
            e[q*4+3] = leaky(pv.w + qp[q*4+3]);
          }
          #pragma unroll
          for(int oi = 0; oi < 8; ++oi){
            float d0 = 0.f, d1 = 0.f;
            #pragma unroll
            for(int q = 0; q < 8; ++q){
              float4v w = *(const float4v*)&WST[2048 + (ob + oi)*32 + q*4];
              d0 = fmaf(w.x, e[q*4+0], d0); d1 = fmaf(w.y, e[q*4+1], d1);
              d0 = fmaf(w.z, e[q*4+2], d0); d1 = fmaf(w.w, e[q*4+3], d1);
            }
            acc[oi] = fmaxf(acc[oi], d0 + d1);
          }
        }
        float y[8];
        #pragma unroll
        for(int oi = 0; oi < 8; ++oi) y[oi] = leaky(acc[oi] + tb[ob + oi]);
        *(float4v*)&XBIG[xcq(n, OUTq[L] + oct*2)     << 2] = *(float4v*)&y[0];
        *(float4v*)&XBIG[xcq(n, OUTq[L] + oct*2 + 1) << 2] = *(float4v*)&y[4];
      }
    } else {
      // layer-3 final: pm = max_k P[j] (first), then Q from Wq, fully unrolled (no scratch)
      if(tid < NPT){
        const int n = tid;
        float pm[32];
        #pragma unroll
        for(int o = 0; o < 32; ++o) pm[o] = -3.4e38f;
        #pragma unroll 1
        for(int k = 0; k < KK; ++k){
          int j = (int)IDXB[n*KK + k];
          #pragma unroll
          for(int q = 0; q < 8; ++q){
            float4v pv = *(const float4v*)&PREG[pq(j, q) << 2];
            pm[q*4+0] = fmaxf(pm[q*4+0], pv.x);
            pm[q*4+1] = fmaxf(pm[q*4+1], pv.y);
            pm[q*4+2] = fmaxf(pm[q*4+2], pv.z);
            pm[q*4+3] = fmaxf(pm[q*4+3], pv.w);
          }
        }
        float xr[32]; loadxg(XBIG, n, XINq[L], xr);
        const float* t5 = p.t[5];
        #pragma unroll
        for(int og = 0; og < 4; ++og){     // FULL unroll: pm indices constant
          float y[8];
          #pragma unroll
          for(int oi = 0; oi < 8; ++oi){
            int o = og*8 + oi;
            float qv = dot32(&WST[1024 + o*32], xr);
            y[oi] = leaky(pm[o] + qv + t5[o]);
          }
          *(float4v*)&XBIG[xcq(n, OUTq[L] + og*2)     << 2] = *(float4v*)&y[0];
          *(float4v*)&XBIG[xcq(n, OUTq[L] + og*2 + 1) << 2] = *(float4v*)&y[4];
        }
      }
    }
    __syncthreads();
  }

  // ---- W6 (512x96) MFMA bf16x3, in-register max over n -> g in WST[0:512) ----
  {
    float4v gmax[8];
    #pragma unroll
    for(int i = 0; i < 8; ++i){ gmax[i][0]=-3.4e38f; gmax[i][1]=-3.4e38f; gmax[i][2]=-3.4e38f; gmax[i][3]=-3.4e38f; }
    #pragma unroll 1
    for(int nt = 0; nt < 7; ++nt){
      int row = nt*16 + l15; if(row > 99) row = 99;   // dup row ok under max
      short8 Bh[3], Bl[3];
      #pragma unroll
      for(int g = 0; g < 3; ++g) buildB2(XBIG, row, g, quad, &Bh[g], &Bl[g]);
      #pragma unroll
      for(int mt = 0; mt < 8; ++mt){      // FULL unroll: gmax indices constant -> no scratch
        const unsigned short* ar = w6b + ((wv*8 + mt)*16 + l15)*288 + quad*8;
        float4v d = {0.f, 0.f, 0.f, 0.f};
        #pragma unroll
        for(int kb = 0; kb < 9; ++kb){
          short8 a = *(const short8*)(ar + kb*32);
          short8 bb = (kb < 3) ? Bh[kb] : ((kb < 6) ? Bl[kb-3] : Bh[kb-6]);
          d = __builtin_amdgcn_mfma_f32_16x16x32_bf16(a, bb, d, 0, 0, 0);
        }
        #pragma unroll
        for(int r = 0; r < 4; ++r) gmax[mt][r] = fmaxf(gmax[mt][r], d[r]);
      }
    }
    #pragma unroll
    for(int mt = 0; mt < 8; ++mt){        // FULL unroll
      float4v m = gmax[mt];
      #pragma unroll
      for(int bit = 1; bit < 16; bit <<= 1){
        m[0] = fmaxf(m[0], __shfl_xor(m[0], bit, 64));
        m[1] = fmaxf(m[1], __shfl_xor(m[1], bit, 64));
        m[2] = fmaxf(m[2], __shfl_xor(m[2], bit, 64));
        m[3] = fmaxf(m[3], __shfl_xor(m[3], bit, 64));
      }
      if(l15 == 0){
        #pragma unroll
        for(int r = 0; r < 4; ++r){
          int o = (wv*8 + mt)*16 + quad*4 + r;
          WST[o] = leaky(m[r] + p.t[6][o]);
        }
      }
    }
  }
  __syncthreads();

  // ---- Rg[o] = W7g . g (128 threads, full 512-dot each) -> WST[512:640) ----
  if(tid < 128){
    const float* wr = &ws[W7G_OFF + tid*512];
    float a0 = 0.f, a1 = 0.f, a2 = 0.f, a3 = 0.f;
    #pragma unroll 4
    for(int c4 = 0; c4 < 128; ++c4){
      float4v w = *(const float4v*)&wr[c4*4];
      float4v g = *(const float4v*)&WST[c4*4];
      a0 = fmaf(w.x, g.x, a0); a1 = fmaf(w.y, g.y, a1);
      a2 = fmaf(w.z, g.z, a2); a3 = fmaf(w.w, g.w, a3);
    }
    WST[512 + tid] = (a0+a1)+(a2+a3);
  }
  __syncthreads();

  // ---- tail: per 16-point chunk: W7(96-part) MFMA -> h2; W8 MFMA; W9 reduce ----
  float* H2 = PREG;   // [16][132]
  #pragma unroll 1
  for(int nc = 0; nc < 7; ++nc){
    int n0 = nc*16;
    int row = n0 + l15; if(row > 99) row = 99;
    {
      short8 Bh[3], Bl[3];
      #pragma unroll
      for(int g = 0; g < 3; ++g) buildB2(XBIG, row, g, quad, &Bh[g], &Bl[g]);
      #pragma unroll 1
      for(int mm = 0; mm < 2; ++mm){
        int Mt = wv*2 + mm;
        const unsigned short* ar = w796 + (Mt*16 + l15)*288 + quad*8;
        float4v d = {0.f, 0.f, 0.f, 0.f};
        #pragma unroll
        for(int kb = 0; kb < 9; ++kb){
          short8 a = *(const short8*)(ar + kb*32);
          short8 bb = (kb < 3) ? Bh[kb] : ((kb < 6) ? Bl[kb-3] : Bh[kb-6]);
          d = __builtin_amdgcn_mfma_f32_16x16x32_bf16(a, bb, d, 0, 0, 0);
        }
        float y[4];
        #pragma unroll
        for(int r = 0; r < 4; ++r){
          int ch = Mt*16 + quad*4 + r;
          y[r] = leaky(d[r] + WST[512 + ch] + p.t[7][ch]);
        }
        *(float4v*)&H2[l15*132 + Mt*16 + quad*4] = *(float4v*)&y[0];
      }
    }
    __syncthreads();
    if(wv < 2){
      short8 Ch[4], Cl[4];
      #pragma unroll
      for(int g = 0; g < 4; ++g) buildB(&H2[l15*132 + g*32 + quad*8], &Ch[g], &Cl[g]);
      const unsigned short* ar = w8b + (wv*16 + l15)*384 + quad*8;
      float4v d = {0.f, 0.f, 0.f, 0.f};
      #pragma unroll
      for(int kb = 0; kb < 12; ++kb){
        short8 a = *(const short8*)(ar + kb*32);
        short8 bb = (kb < 4) ? Ch[kb] : ((kb < 8) ? Cl[kb-4] : Ch[kb-8]);
        d = __builtin_amdgcn_mfma_f32_16x16x32_bf16(a, bb, d, 0, 0, 0);
      }
      float partial = 0.f;
      #pragma unroll
      for(int r = 0; r < 4; ++r){
        int o = wv*16 + quad*4 + r;
        float h3 = leaky(d[r] + p.t[8][o]);
        partial = fmaf(p.W9[o], h3, partial);
      }
      partial += __shfl_xor(partial, 16, 64);
      partial += __shfl_xor(partial, 32, 64);
      if(lane < 16) TMP[wv*16 + lane] = partial;
    }
    __syncthreads();
    if(tid < 16 && (n0 + tid) < NPT)
      p.out[(size_t)b*NPT + n0 + tid] = TMP[tid] + TMP[16 + tid];
    __syncthreads();
  }
}

extern "C" void kernel_launch(void* const* d_in, const int* in_sizes, int n_in,
                              void* d_out, int out_size, void* d_ws, size_t ws_size,
                              hipStream_t stream) {
  (void)n_in; (void)out_size; (void)ws_size;
  PrepP pp;
  for(int i = 0; i < 9; ++i) pp.W[i] = (const float*)d_in[1 + i];
  for(int i = 0; i < 9; ++i) pp.s[i] = (const float*)d_in[11 + 2*i];
  pp.ws = (float*)d_ws;
  prep_kernel<<<256, 256, 0, stream>>>(pp);

  MainP mp;
  mp.obs = (const float*)d_in[0];
  mp.W9  = (const float*)d_in[10];
  for(int i = 0; i < 9; ++i) mp.t[i] = (const float*)d_in[12 + 2*i];
  mp.ws  = (const float*)d_ws;
  mp.out = (float*)d_out;
  const int B = in_sizes[0] / 3000;
  dgcnn<<<B, 256, 0, stream>>>(mp);
}

// Round 6
// 894.887 us; speedup vs baseline: 2.3056x; 1.2826x over previous
//
#include <hip/hip_runtime.h>

#define NPT 100
#define KK 10

typedef __attribute__((ext_vector_type(8))) short short8;
typedef __attribute__((ext_vector_type(4))) float float4v;

__device__ __forceinline__ float leaky(float v){ return fmaxf(v, 0.2f*v); }
__device__ __forceinline__ unsigned short bf16r(float x){
  unsigned u = __float_as_uint(x);
  return (unsigned short)((u + 0x7FFFu + ((u>>16)&1u)) >> 16);
}
__device__ __forceinline__ float bf2f(unsigned short h){ return __uint_as_float(((unsigned)h)<<16); }

// d_ws layout (identical to round 5). float offsets:
#define WV(w) (1024*(w))        // 9 folded 32x32 fp32 mats: W0f,Wp1,Wq1,W2f,Wp3,Wq3,W4f,Wp5,Wq5
#define W7G_OFF 9216            // W7 g-part folded fp32 [128][512]
// byte offsets:
#define W6B_OFF   299008        // W6 folded bf16 [512][288]  (kb 0-2 hi, 3-5 hi, 6-8 lo)
#define W796B_OFF 593920        // W7 96-part folded bf16 [128][288]
#define W8B_OFF   667648        // W8 folded bf16 [32][384]   (kb 0-3 hi, 4-7 hi, 8-11 lo)

struct PrepP {
  const float* W[9];
  const float* s[9];
  float* ws;
};

__global__ __launch_bounds__(256) void prep_kernel(PrepP p){
  int gid = blockIdx.x*256 + threadIdx.x;
  int gs = gridDim.x*256;
  float* ws = p.ws;
  unsigned short* w6b  = (unsigned short*)((char*)ws + W6B_OFF);
  unsigned short* w796 = (unsigned short*)((char*)ws + W796B_OFF);
  unsigned short* w8b  = (unsigned short*)((char*)ws + W8B_OFF);
  for(int i = gid; i < 9216; i += gs){
    int w = i >> 10, r = i & 1023, o = r >> 5, c = r & 31;
    float v = 0.f;
    switch(w){
      case 0: v = (c < 30) ? p.s[0][o]*p.W[0][o*30 + c] : 0.f; break;
      case 1: v = p.s[1][o]*p.W[1][o*64 + c]; break;
      case 2: v = p.s[1][o]*(p.W[1][o*64 + 32 + c] - p.W[1][o*64 + c]); break;
      case 3: v = p.s[2][o]*p.W[2][o*32 + c]; break;
      case 4: v = p.s[3][o]*p.W[3][o*64 + c]; break;
      case 5: v = p.s[3][o]*(p.W[3][o*64 + 32 + c] - p.W[3][o*64 + c]); break;
      case 6: v = p.s[4][o]*p.W[4][o*32 + c]; break;
      case 7: v = p.s[5][o]*p.W[5][o*64 + c]; break;
      case 8: v = p.s[5][o]*(p.W[5][o*64 + 32 + c] - p.W[5][o*64 + c]); break;
    }
    ws[i] = v;
  }
  for(int i = gid; i < 65536; i += gs){
    int o = i >> 9, c = i & 511;
    ws[W7G_OFF + i] = p.s[7][o]*p.W[7][o*608 + c];
  }
  for(int i = gid; i < 147456; i += gs){
    int o = i/288, cc = i - o*288, kb = cc >> 5, k = cc & 31;
    int sc = (kb % 3)*32 + k;
    float w = p.s[6][o]*p.W[6][o*96 + sc];
    unsigned short h = bf16r(w);
    w6b[i] = (kb < 6) ? h : bf16r(w - bf2f(h));
  }
  for(int i = gid; i < 36864; i += gs){
    int o = i/288, cc = i - o*288, kb = cc >> 5, k = cc & 31;
    int sc = 512 + (kb % 3)*32 + k;
    float w = p.s[7][o]*p.W[7][o*608 + sc];
    unsigned short h = bf16r(w);
    w796[i] = (kb < 6) ? h : bf16r(w - bf2f(h));
  }
  for(int i = gid; i < 12288; i += gs){
    int o = i/384, cc = i - o*384, kb = cc >> 5, k = cc & 31;
    int sc = (kb & 3)*32 + k;
    float w = p.s[8][o]*p.W[8][o*128 + sc];
    unsigned short h = bf16r(w);
    w8b[i] = (kb < 8) ? h : bf16r(w - bf2f(h));
  }
}

// XBIG: [100][96] as 24 quads/row, XOR-swizzled within 8-quad groups
__device__ __forceinline__ int xcq(int n, int q){ return n*24 + (q ^ (n & 7)); }
// PREG P: [100][32] as 8 quads/row, swizzled
__device__ __forceinline__ int pq(int j, int q){ return j*8 + (q ^ (j & 7)); }
// knn scratch slot -> raw float index inside out-group of row n
__device__ __forceinline__ int vf(int n, int oq, int s){
  return (xcq(n, oq + (s >> 2)) << 2) | (s & 3);
}

__device__ __forceinline__ void loadxg(const float* XB, int row, int gq, float* xr){
  #pragma unroll
  for(int q = 0; q < 8; ++q){
    float4v v = *(const float4v*)&XB[xcq(row, gq + q) << 2];
    xr[q*4+0] = v.x; xr[q*4+1] = v.y; xr[q*4+2] = v.z; xr[q*4+3] = v.w;
  }
}
__device__ __forceinline__ float dot32(const float* wrow, const float* xr){
  float a0 = 0.f, a1 = 0.f, a2 = 0.f, a3 = 0.f;
  #pragma unroll
  for(int q = 0; q < 8; ++q){
    float4v w = *(const float4v*)&wrow[q*4];
    a0 = fmaf(w.x, xr[q*4+0], a0);
    a1 = fmaf(w.y, xr[q*4+1], a1);
    a2 = fmaf(w.z, xr[q*4+2], a2);
    a3 = fmaf(w.w, xr[q*4+3], a3);
  }
  return (a0+a1)+(a2+a3);
}
__device__ __forceinline__ void packbf(float4v v0, float4v v1, short8* bh, short8* bl){
  float xv[8] = {v0.x, v0.y, v0.z, v0.w, v1.x, v1.y, v1.z, v1.w};
  short8 h, l;
  #pragma unroll
  for(int j = 0; j < 8; ++j){
    unsigned short hh = bf16r(xv[j]);
    h[j] = (short)hh;
    l[j] = (short)bf16r(xv[j] - bf2f(hh));
  }
  *bh = h; *bl = l;
}
// bf16 hi/lo fragments from swizzled XBIG group g (8 elems at quad*8)
__device__ __forceinline__ void buildB2(const float* XB, int row, int g, int quad,
                                        short8* bh, short8* bl){
  float4v v0 = *(const float4v*)&XB[xcq(row, g*8 + quad*2)     << 2];
  float4v v1 = *(const float4v*)&XB[xcq(row, g*8 + quad*2 + 1) << 2];
  packbf(v0, v1, bh, bl);
}

struct MainP {
  const float* obs;
  const float* W9;
  const float* t[9];
  const float* ws;
  float* out;
};

__global__ __launch_bounds__(256, 2) void dgcnn(MainP p){
  const int b = blockIdx.x;
  const int tid = threadIdx.x;
  const int lane = tid & 63, wv = tid >> 6;
  const int quad = lane >> 4, l15 = lane & 15;

  // LDS: 38400 + 12800 + 12800 + 512 + 1000 = 65512 B
  __shared__ __align__(16) float XBIG[9600];   // x-cat [100][96] swizzled; out-group hosts knn scratch
  __shared__ __align__(16) float PREG[3200];   // P[100][32] -> (W6: g[0:512)+GW[512:640)) -> H2[25][128]
  __shared__ __align__(16) float WST[3200];    // Wp|Wq|xx|conv-w  /  staged weight tile
  __shared__ __align__(16) float RGB[128];     // Rg
  __shared__ __align__(16) unsigned char IDXB[1000];  // knn idx -> tail TMP floats
  short* WSTs = (short*)WST;
  float* TMPf = (float*)IDXB;

  const float* ws = p.ws;
  const unsigned short* w6b  = (const unsigned short*)((const char*)ws + W6B_OFF);
  const unsigned short* w796 = (const unsigned short*)((const char*)ws + W796B_OFF);
  const unsigned short* w8b  = (const unsigned short*)((const char*)ws + W8B_OFF);

  // ---- stage obs -> XBIG group 0 + W0f ----
  for(int i = tid; i < 3200; i += 256){
    int n = i >> 5, c = i & 31;
    float v = (c < 30) ? p.obs[(size_t)b*3000 + n*30 + c] : 0.f;
    XBIG[(xcq(n, c >> 2) << 2) | (c & 3)] = v;
  }
  for(int i = tid; i < 1024; i += 256) WST[i] = ws[WV(0) + i];
  __syncthreads();

  // ---- conv0: group0(obs) -> group2(x0) ----
  {
    int oh = tid >> 7, n = tid & 127;
    if(n < NPT){
      float xr[32]; loadxg(XBIG, n, 0, xr);
      float o16[16];
      #pragma unroll
      for(int oi = 0; oi < 16; ++oi){
        int o = oh*16 + oi;
        o16[oi] = leaky(dot32(&WST[o*32], xr) + p.t[0][o]);
      }
      #pragma unroll
      for(int q = 0; q < 4; ++q)
        *(float4v*)&XBIG[xcq(n, 16 + oh*4 + q) << 2] = *(float4v*)&o16[q*4];
    }
  }
  __syncthreads();

  // ---- 3 edge layers ----
  const int XINq[3] = {16, 0, 8};
  const int QOFq[3] = {8, 16, 0};
  const int OUTq[3] = {0, 8, 16};
  const int WPI[3]  = {1, 4, 7};

  for(int L = 0; L < 3; ++L){
    const int xin = XINq[L], qof = QOFq[L], outq = OUTq[L];
    const int UT = (L < 2) ? 800 : 400;
    const float* ta = p.t[1 + 2*L];

    // S1: stage Wp+Wq (+conv-w); xx
    for(int i = tid; i < 2048; i += 256) WST[i] = ws[WV(WPI[L]) + i];
    if(L < 2){
      int wci = (L == 0) ? 3 : 6;
      for(int i = tid; i < 1024; i += 256) WST[2148 + i] = ws[WV(wci) + i];
    }
    if(tid < NPT){
      float xr[32]; loadxg(XBIG, tid, xin, xr);
      float a = 0.f;
      #pragma unroll
      for(int c = 0; c < 32; ++c) a = fmaf(xr[c], xr[c], a);
      WST[2048 + tid] = a;
    }
    __syncthreads();

    // S2: knn half A (t0-99) | half B (t100-199) | P units (t200-255)
    if(tid < 200){
      const int h = (tid < 100) ? 0 : 1;
      const int n = tid - h*100;
      float xr[32]; loadxg(XBIG, n, xin, xr);
      const float xxn = WST[2048 + n];
      float bv[KK]; int bj[KK];
      #pragma unroll
      for(int k = 0; k < KK; ++k){ bv[k] = -3.4e38f; bj[k] = 0; }
      const int m0 = h*50;
      #pragma unroll 1
      for(int m = m0; m < m0 + 50; ++m){
        float a0 = 0.f, a1 = 0.f, a2 = 0.f, a3 = 0.f;
        #pragma unroll
        for(int q = 0; q < 8; ++q){
          float4v v = *(const float4v*)&XBIG[xcq(m, xin + q) << 2];
          a0 = fmaf(xr[q*4+0], v.x, a0);
          a1 = fmaf(xr[q*4+1], v.y, a1);
          a2 = fmaf(xr[q*4+2], v.z, a2);
          a3 = fmaf(xr[q*4+3], v.w, a3);
        }
        float d = 2.0f*((a0+a1)+(a2+a3)) - xxn - WST[2048 + m];
        if(d > bv[KK-1]){   // strict >: earlier m wins ties within half
          float cv = d; int ci = m;
          #pragma unroll
          for(int jj = 0; jj < KK; ++jj){
            bool sw = cv > bv[jj];
            float tv = bv[jj]; int ti = bj[jj];
            bv[jj] = sw ? cv : tv; bj[jj] = sw ? ci : ti;
            cv = sw ? tv : cv;    ci = sw ? ti : ci;
          }
        }
      }
      #pragma unroll
      for(int k = 0; k < KK; ++k) XBIG[vf(n, outq, h*10 + k)] = bv[k];
      unsigned w0 = (unsigned)bj[0] | ((unsigned)bj[1]<<8) | ((unsigned)bj[2]<<16) | ((unsigned)bj[3]<<24);
      unsigned w1 = (unsigned)bj[4] | ((unsigned)bj[5]<<8) | ((unsigned)bj[6]<<16) | ((unsigned)bj[7]<<24);
      unsigned w2 = (unsigned)bj[8] | ((unsigned)bj[9]<<8);
      XBIG[vf(n, outq, 20 + h*3 + 0)] = __uint_as_float(w0);
      XBIG[vf(n, outq, 20 + h*3 + 1)] = __uint_as_float(w1);
      XBIG[vf(n, outq, 20 + h*3 + 2)] = __uint_as_float(w2);
    } else {
      #pragma unroll 1
      for(int k = 0; k < 2; ++k){
        int u = (tid - 200) + 56*k;        // units 0..111 (all P: t<2)
        int t = u/100, j = u - t*100;
        float xr[32]; loadxg(XBIG, j, xin, xr);
        float o8[8];
        #pragma unroll
        for(int oi = 0; oi < 8; ++oi) o8[oi] = dot32(&WST[(t*8 + oi)*32], xr);
        *(float4v*)&PREG[pq(j, t*2)     << 2] = *(float4v*)&o8[0];
        *(float4v*)&PREG[pq(j, t*2 + 1) << 2] = *(float4v*)&o8[4];
      }
    }
    __syncthreads();

    // S3: merge (t0-99) | remaining P/Q units (t100-255)
    if(tid < 100){
      const int n = tid;
      int ia = 0, ib = 0;
      #pragma unroll 1
      for(int k = 0; k < KK; ++k){
        float va = XBIG[vf(n, outq, ia)];
        float vb = XBIG[vf(n, outq, 10 + ib)];
        bool takeb = (ib < 10) && ((ia >= 10) || (vb > va));
        int pos = takeb ? ib : ia;
        int wslot = takeb ? (23 + (pos >> 2)) : (20 + (pos >> 2));
        unsigned w = __float_as_uint(XBIG[vf(n, outq, wslot)]);
        IDXB[n*KK + k] = (unsigned char)((w >> ((pos & 3)*8)) & 255u);
        ia += takeb ? 0 : 1;
        ib += takeb ? 1 : 0;
      }
    } else {
      #pragma unroll 1
      for(int u = 112 + (tid - 100); u < UT; u += 156){
        int t = u/100, j = u - t*100;
        float xr[32]; loadxg(XBIG, j, xin, xr);
        float o8[8];
        if(t < 4){
          #pragma unroll
          for(int oi = 0; oi < 8; ++oi) o8[oi] = dot32(&WST[(t*8 + oi)*32], xr);
          *(float4v*)&PREG[pq(j, t*2)     << 2] = *(float4v*)&o8[0];
          *(float4v*)&PREG[pq(j, t*2 + 1) << 2] = *(float4v*)&o8[4];
        } else {
          int og = t - 4;
          #pragma unroll
          for(int oi = 0; oi < 8; ++oi)
            o8[oi] = dot32(&WST[1024 + (og*8 + oi)*32], xr) + ta[og*8 + oi];  // Q' = Q + t_a
          *(float4v*)&XBIG[xcq(j, qof + og*2)     << 2] = *(float4v*)&o8[0];
          *(float4v*)&XBIG[xcq(j, qof + og*2 + 1) << 2] = *(float4v*)&o8[4];
        }
      }
    }
    __syncthreads();

    // S4
    if(L < 2){
      const float* tb = p.t[2 + 2*L];
      #pragma unroll 1
      for(int it = tid; it < 400; it += 256){
        int n = it % 100, oct = it / 100, ob = oct*8;
        float acc[8];
        #pragma unroll
        for(int o = 0; o < 8; ++o) acc[o] = -3.4e38f;
        #pragma unroll 1
        for(int k = 0; k < KK; k += 2){
          int j0 = (int)IDXB[n*KK + k];
          int j1 = (int)IDXB[n*KK + k + 1];
          float e0[32], e1[32];
          #pragma unroll
          for(int q = 0; q < 8; ++q){
            float4v qv = *(const float4v*)&XBIG[xcq(n, qof + q) << 2];  // Q' incl t_a
            float4v p0 = *(const float4v*)&PREG[pq(j0, q) << 2];
            float4v p1 = *(const float4v*)&PREG[pq(j1, q) << 2];
            e0[q*4+0] = leaky(p0.x + qv.x); e1[q*4+0] = leaky(p1.x + qv.x);
            e0[q*4+1] = leaky(p0.y + qv.y); e1[q*4+1] = leaky(p1.y + qv.y);
            e0[q*4+2] = leaky(p0.z + qv.z); e1[q*4+2] = leaky(p1.z + qv.z);
            e0[q*4+3] = leaky(p0.w + qv.w); e1[q*4+3] = leaky(p1.w + qv.w);
          }
          #pragma unroll
          for(int oi = 0; oi < 8; ++oi){
            float d0 = 0.f, d1 = 0.f, d2 = 0.f, d3 = 0.f;
            #pragma unroll
            for(int q = 0; q < 8; ++q){
              float4v w = *(const float4v*)&WST[2148 + (ob + oi)*32 + q*4];
              d0 = fmaf(w.x, e0[q*4+0], d0); d1 = fmaf(w.y, e0[q*4+1], d1);
              d0 = fmaf(w.z, e0[q*4+2], d0); d1 = fmaf(w.w, e0[q*4+3], d1);
              d2 = fmaf(w.x, e1[q*4+0], d2); d3 = fmaf(w.y, e1[q*4+1], d3);
              d2 = fmaf(w.z, e1[q*4+2], d2); d3 = fmaf(w.w, e1[q*4+3], d3);
            }
            acc[oi] = fmaxf(acc[oi], fmaxf(d0 + d1, d2 + d3));
          }
        }
        float y[8];
        #pragma unroll
        for(int oi = 0; oi < 8; ++oi) y[oi] = leaky(acc[oi] + tb[ob + oi]);
        *(float4v*)&XBIG[xcq(n, outq + oct*2)     << 2] = *(float4v*)&y[0];
        *(float4v*)&XBIG[xcq(n, outq + oct*2 + 1) << 2] = *(float4v*)&y[4];
      }
    } else {
      // layer-3 final: pm first, then Q inline, fully unrolled
      if(tid < NPT){
        const int n = tid;
        float pm[32];
        #pragma unroll
        for(int o = 0; o < 32; ++o) pm[o] = -3.4e38f;
        #pragma unroll 1
        for(int k = 0; k < KK; ++k){
          int j = (int)IDXB[n*KK + k];
          #pragma unroll
          for(int q = 0; q < 8; ++q){
            float4v pv = *(const float4v*)&PREG[pq(j, q) << 2];
            pm[q*4+0] = fmaxf(pm[q*4+0], pv.x);
            pm[q*4+1] = fmaxf(pm[q*4+1], pv.y);
            pm[q*4+2] = fmaxf(pm[q*4+2], pv.z);
            pm[q*4+3] = fmaxf(pm[q*4+3], pv.w);
          }
        }
        float xr[32]; loadxg(XBIG, n, xin, xr);
        const float* t5 = p.t[5];
        #pragma unroll
        for(int og = 0; og < 4; ++og){
          float y[8];
          #pragma unroll
          for(int oi = 0; oi < 8; ++oi){
            int o = og*8 + oi;
            float qv = dot32(&WST[1024 + o*32], xr);
            y[oi] = leaky(pm[o] + qv + t5[o]);
          }
          *(float4v*)&XBIG[xcq(n, outq + og*2)     << 2] = *(float4v*)&y[0];
          *(float4v*)&XBIG[xcq(n, outq + og*2 + 1) << 2] = *(float4v*)&y[4];
        }
      }
    }
    __syncthreads();
  }

  // ================= W6 (512x96) MFMA, LDS-staged tiles, pipelined reduce =================
  {
    const int nt0 = wv, nt1 = (wv + 4 < 7) ? wv + 4 : 6;
    int r0 = nt0*16 + l15; if(r0 > 99) r0 = 99;
    int r1 = nt1*16 + l15; if(r1 > 99) r1 = 99;
    short8 B0h[3], B0l[3], B1h[3], B1l[3];
    #pragma unroll
    for(int g = 0; g < 3; ++g){
      buildB2(XBIG, r0, g, quad, &B0h[g], &B0l[g]);
      buildB2(XBIG, r1, g, quad, &B1h[g], &B1l[g]);
    }
    #pragma unroll 1
    for(int Mt = 0; Mt < 32; ++Mt){
      // stage tile Mt: 16 rows x 288 bf16 -> LDS rows padded to 296
      #pragma unroll
      for(int k = 0; k < 3; ++k){
        int c = tid + 256*k;
        if(c < 576){
          short8 v = *(const short8*)(w6b + Mt*4608 + c*8);
          int row = c/36, cc = c - row*36;
          *(short8*)&WSTs[row*296 + cc*8] = v;
        }
      }
      if(Mt > 0 && tid < 16){   // finalize Mt-1 from GW
        int pb = (Mt - 1) & 1;
        float m = fmaxf(fmaxf(PREG[512 + pb*64 + tid], PREG[512 + pb*64 + 16 + tid]),
                        fmaxf(PREG[512 + pb*64 + 32 + tid], PREG[512 + pb*64 + 48 + tid]));
        int o = (Mt - 1)*16 + tid;
        PREG[o] = leaky(m + p.t[6][o]);
      }
      __syncthreads();
      float4v d0 = {0.f,0.f,0.f,0.f}, d1 = {0.f,0.f,0.f,0.f};
      #pragma unroll
      for(int kb = 0; kb < 9; ++kb){
        short8 a = *(const short8*)&WSTs[l15*296 + kb*32 + quad*8];
        short8 b0 = (kb < 3) ? B0h[kb] : ((kb < 6) ? B0l[kb-3] : B0h[kb-6]);
        short8 b1 = (kb < 3) ? B1h[kb] : ((kb < 6) ? B1l[kb-3] : B1h[kb-6]);
        d0 = __builtin_amdgcn_mfma_f32_16x16x32_bf16(a, b0, d0, 0, 0, 0);
        d1 = __builtin_amdgcn_mfma_f32_16x16x32_bf16(a, b1, d1, 0, 0, 0);
      }
      float4v dm;
      #pragma unroll
      for(int r = 0; r < 4; ++r) dm[r] = fmaxf(d0[r], d1[r]);
      #pragma unroll
      for(int bit = 1; bit < 16; bit <<= 1){
        dm[0] = fmaxf(dm[0], __shfl_xor(dm[0], bit, 64));
        dm[1] = fmaxf(dm[1], __shfl_xor(dm[1], bit, 64));
        dm[2] = fmaxf(dm[2], __shfl_xor(dm[2], bit, 64));
        dm[3] = fmaxf(dm[3], __shfl_xor(dm[3], bit, 64));
      }
      if(l15 == 0) *(float4v*)&PREG[512 + (Mt&1)*64 + wv*16 + quad*4] = dm;
      __syncthreads();
    }
    if(tid < 16){   // finalize Mt=31
      int pb = 31 & 1;
      float m = fmaxf(fmaxf(PREG[512 + pb*64 + tid], PREG[512 + pb*64 + 16 + tid]),
                      fmaxf(PREG[512 + pb*64 + 32 + tid], PREG[512 + pb*64 + 48 + tid]));
      int o = 31*16 + tid;
      PREG[o] = leaky(m + p.t[6][o]);
    }
  }
  __syncthreads();

  // ================= Rg = W7g . g (coalesced, wave per 32 rows) -> RGB =================
  {
    float4v g0 = *(const float4v*)&PREG[lane*4];
    float4v g1 = *(const float4v*)&PREG[256 + lane*4];
    #pragma unroll 1
    for(int i = 0; i < 32; ++i){
      int o = wv*32 + i;
      float4v w0 = *(const float4v*)&ws[W7G_OFF + o*512 + lane*4];
      float4v w1 = *(const float4v*)&ws[W7G_OFF + o*512 + 256 + lane*4];
      float a = fmaf(w0.x, g0.x, fmaf(w0.y, g0.y, fmaf(w0.z, g0.z, fmaf(w0.w, g0.w,
                fmaf(w1.x, g1.x, fmaf(w1.y, g1.y, fmaf(w1.z, g1.z, fmaf(w1.w, g1.w, 0.f))))))));
      #pragma unroll
      for(int sh = 32; sh >= 1; sh >>= 1) a += __shfl_xor(a, sh, 64);
      if(lane == 0) RGB[o] = a;
    }
  }
  __syncthreads();

  // ================= tail: nc chunks of 25 points; W7(96) + W8 + W9 =================
  #pragma unroll 1
  for(int nc = 0; nc < 4; ++nc){
    const int rg = wv & 1;
    const int hrow = rg ? 9 + l15 : l15;        // local row 0..24 (rows 9-15 dup: benign)
    const int grow = nc*25 + hrow;              // global row <= 99
    short8 Xh[3], Xl[3];
    #pragma unroll
    for(int g = 0; g < 3; ++g) buildB2(XBIG, grow, g, quad, &Xh[g], &Xl[g]);

    // W7 96-part: 8 M-tiles, LDS-staged
    #pragma unroll 1
    for(int Mt = 0; Mt < 8; ++Mt){
      #pragma unroll
      for(int k = 0; k < 3; ++k){
        int c = tid + 256*k;
        if(c < 576){
          short8 v = *(const short8*)(w796 + Mt*4608 + c*8);
          int row = c/36, cc = c - row*36;
          *(short8*)&WSTs[row*296 + cc*8] = v;
        }
      }
      __syncthreads();
      if((wv >> 1) == (Mt & 1)){
        float4v d = {0.f,0.f,0.f,0.f};
        #pragma unroll
        for(int kb = 0; kb < 9; ++kb){
          short8 a = *(const short8*)&WSTs[l15*296 + kb*32 + quad*8];
          short8 bb = (kb < 3) ? Xh[kb] : ((kb < 6) ? Xl[kb-3] : Xh[kb-6]);
          d = __builtin_amdgcn_mfma_f32_16x16x32_bf16(a, bb, d, 0, 0, 0);
        }
        float4v y;
        #pragma unroll
        for(int r = 0; r < 4; ++r){
          int o = Mt*16 + quad*4 + r;
          y[r] = leaky(d[r] + RGB[o] + p.t[7][o]);
        }
        int q = Mt*4 + quad;
        *(float4v*)&PREG[(hrow*32 + (q ^ (hrow & 7))) << 2] = y;
      }
      __syncthreads();
    }

    // W8 frags from H2 (hi/lo)
    short8 Hh[4], Hl[4];
    #pragma unroll
    for(int kb = 0; kb < 4; ++kb){
      int q0 = kb*8 + quad*2;
      float4v v0 = *(const float4v*)&PREG[(hrow*32 + (q0       ^ (hrow & 7))) << 2];
      float4v v1 = *(const float4v*)&PREG[(hrow*32 + ((q0 + 1) ^ (hrow & 7))) << 2];
      packbf(v0, v1, &Hh[kb], &Hl[kb]);
    }
    #pragma unroll 1
    for(int M8 = 0; M8 < 2; ++M8){
      #pragma unroll
      for(int k = 0; k < 3; ++k){
        int c = tid + 256*k;   // 768 chunks, rows padded to 392
        if(c < 768){
          short8 v = *(const short8*)(w8b + M8*6144 + c*8);
          int row = c/48, cc = c - row*48;
          *(short8*)&WSTs[row*392 + cc*8] = v;
        }
      }
      __syncthreads();
      if((wv >> 1) == M8){
        float4v d = {0.f,0.f,0.f,0.f};
        #pragma unroll
        for(int kb = 0; kb < 12; ++kb){
          short8 a = *(const short8*)&WSTs[l15*392 + kb*32 + quad*8];
          short8 bb = (kb < 4) ? Hh[kb] : ((kb < 8) ? Hl[kb-4] : Hh[kb-8]);
          d = __builtin_amdgcn_mfma_f32_16x16x32_bf16(a, bb, d, 0, 0, 0);
        }
        float partial = 0.f;
        #pragma unroll
        for(int r = 0; r < 4; ++r){
          int o = M8*16 + quad*4 + r;
          partial = fmaf(p.W9[o], leaky(d[r] + p.t[8][o]), partial);
        }
        partial += __shfl_xor(partial, 16, 64);
        partial += __shfl_xor(partial, 32, 64);
        if(lane < 16) TMPf[M8*25 + hrow] = partial;
      }
      __syncthreads();
    }
    if(tid < 25)
      p.out[(size_t)b*NPT + nc*25 + tid] = TMPf[tid] + TMPf[25 + tid];
    __syncthreads();
  }
}

extern "C" void kernel_launch(void* const* d_in, const int* in_sizes, int n_in,
                              void* d_out, int out_size, void* d_ws, size_t ws_size,
                              hipStream_t stream) {
  (void)n_in; (void)out_size; (void)ws_size;
  PrepP pp;
  for(int i = 0; i < 9; ++i) pp.W[i] = (const float*)d_in[1 + i];
  for(int i = 0; i < 9; ++i) pp.s[i] = (const float*)d_in[11 + 2*i];
  pp.ws = (float*)d_ws;
  prep_kernel<<<256, 256, 0, stream>>>(pp);

  MainP mp;
  mp.obs = (const float*)d_in[0];
  mp.W9  = (const float*)d_in[10];
  for(int i = 0; i < 9; ++i) mp.t[i] = (const float*)d_in[12 + 2*i];
  mp.ws  = (const float*)d_ws;
  mp.out = (float*)d_out;
  const int B = in_sizes[0] / 3000;
  dgcnn<<<B, 256, 0, stream>>>(mp);
}